// Round 11
// baseline (2652.740 us; speedup 1.0000x reference)
//
#include <hip/hip_runtime.h>
#include <math.h>

#define BSZ 512
#define TT  100
#define NDD 10
#define DSS 6
#define INS 256
#define HID 256
#define CAT 2816   // INS*NDD + HID
#define KZ  320
#define NOUTP 320
#define NOUT 266

typedef short sh8 __attribute__((ext_vector_type(8)));
typedef float f4  __attribute__((ext_vector_type(4)));
typedef unsigned int u4 __attribute__((ext_vector_type(4)));
typedef unsigned short ushort_t;

__device__ __forceinline__ float sigf(float x) { return 1.0f / (1.0f + expf(-x)); }

__device__ __forceinline__ ushort_t f2bf(float f) {
    union { float f; unsigned int u; } v; v.f = f;
    unsigned int r = (v.u + 0x7FFFu + ((v.u >> 16) & 1u)) >> 16;
    return (ushort_t)r;
}

#define MFMA(a, b, c) __builtin_amdgcn_mfma_f32_16x16x32_bf16((a), (b), (c), 0, 0, 0)
#define ALOAD(p)    __hip_atomic_load((p), __ATOMIC_RELAXED, __HIP_MEMORY_SCOPE_AGENT)
#define ASTORE(p,v) __hip_atomic_store((p), (v), __ATOMIC_RELAXED, __HIP_MEMORY_SCOPE_AGENT)

// sc1 loads bypass L1/L2 (agent-coherent, matches sc1 store visibility).
// "=&v" earlyclobber MANDATORY (round-7 crash).
__device__ __forceinline__ u4 aload16(const unsigned int* p) {
    u4 r;
    asm volatile("global_load_dwordx4 %0, %1, off sc0 sc1\n\ts_waitcnt vmcnt(0)"
                 : "=&v"(r) : "v"(p) : "memory");
    return r;
}
__device__ __forceinline__ void aload16x2(u4* a, const unsigned int* p0,
                                          const unsigned int* p1) {
    asm volatile(
        "global_load_dwordx4 %0, %2, off sc0 sc1\n\t"
        "global_load_dwordx4 %1, %3, off sc0 sc1\n\t"
        "s_waitcnt vmcnt(0)"
        : "=&v"(a[0]), "=&v"(a[1]) : "v"(p0), "v"(p1) : "memory");
}
__device__ __forceinline__ void aload16x4(f4* a, const float* p0, const float* p1,
                                          const float* p2, const float* p3) {
    asm volatile(
        "global_load_dwordx4 %0, %4, off sc0 sc1\n\t"
        "global_load_dwordx4 %1, %5, off sc0 sc1\n\t"
        "global_load_dwordx4 %2, %6, off sc0 sc1\n\t"
        "global_load_dwordx4 %3, %7, off sc0 sc1\n\t"
        "s_waitcnt vmcnt(0)"
        : "=&v"(a[0]), "=&v"(a[1]), "=&v"(a[2]), "=&v"(a[3])
        : "v"(p0), "v"(p1), "v"(p2), "v"(p3)
        : "memory");
}

// ---------------------------------------------------------------------------
// Precompute kernels (unchanged, validated)
// ---------------------------------------------------------------------------
__global__ __launch_bounds__(64) void k_fold(
    const float* __restrict__ W1, const float* __restrict__ Wd,
    const float* __restrict__ bd, const float* __restrict__ b1,
    ushort_t* __restrict__ Wzc, float* __restrict__ bfold)
{
    __shared__ float sW1[2560];
    __shared__ float sWd[INS * DSS];
    __shared__ float red[64];
    const int j = blockIdx.x;
    const int tid = threadIdx.x;
    for (int f = tid; f < INS * DSS; f += 64) sWd[f] = Wd[f];
    for (int f = tid; f < 2560; f += 64) sW1[f] = W1[(size_t)j * CAT + f];
    __syncthreads();
    if (tid < 60) {
        int n = tid / DSS, d = tid - n * DSS;
        float acc = 0.f;
        for (int i = 0; i < INS; ++i) acc += sW1[n * INS + i] * sWd[i * DSS + d];
        Wzc[j * KZ + tid] = f2bf(acc);
    } else {
        Wzc[j * KZ + tid] = 0;
    }
    for (int q = tid; q < HID; q += 64)
        Wzc[j * KZ + 64 + q] = f2bf(W1[(size_t)j * CAT + 2560 + q]);
    float acc = 0.f;
    for (int p = tid; p < 2560; p += 64) acc += sW1[p] * bd[p & (INS - 1)];
    red[tid] = acc;
    __syncthreads();
    for (int s = 32; s > 0; s >>= 1) {
        if (tid < s) red[tid] += red[tid + s];
        __syncthreads();
    }
    if (tid == 0) bfold[j] = b1[j] + red[0];
}

__global__ __launch_bounds__(256) void k_dfold(
    const float* __restrict__ desc, ushort_t* __restrict__ Dfold)
{
    int idx = blockIdx.x * 256 + threadIdx.x;
    int p = idx & 63;
    int tb = idx >> 6;
    int t = tb / BSZ;
    int b = tb - t * BSZ;
    float v = (p < 60) ? desc[(size_t)b * (TT * 60) + t * 60 + p] : 0.f;
    Dfold[idx] = f2bf(v);
}

__global__ __launch_bounds__(256) void k_prep_g(
    const float* __restrict__ Wih, const float* __restrict__ Whh,
    const float* __restrict__ bih, const float* __restrict__ bhh,
    ushort_t* __restrict__ Wg, float* __restrict__ bg)
{
    int idx = blockIdx.x * 256 + threadIdx.x;   // 1024*512
    int newr = idx >> 9, k = idx & 511;
    int j = newr >> 2, g = newr & 3;
    int src_row = g * 256 + j;
    float v = (k < 256) ? Wih[(size_t)src_row * INS + k]
                        : Whh[(size_t)src_row * HID + (k - 256)];
    Wg[idx] = f2bf(v);
    if (k == 0) bg[newr] = bih[src_row] + bhh[src_row];
}

__global__ __launch_bounds__(256) void k_prep_o(
    const float* __restrict__ W2, const float* __restrict__ Wv,
    ushort_t* __restrict__ Wout)
{
    int idx = blockIdx.x * 256 + threadIdx.x;   // 320*2816
    int r = idx / CAT, k = idx - r * CAT;
    float v = 0.f;
    if (r < 256) v = W2[(size_t)r * CAT + k];
    else if (r < NOUT) v = Wv[(size_t)(r - 256) * CAT + k];
    Wout[idx] = f2bf(v);
}

// ---------------------------------------------------------------------------
// Flag-array group barriers. Epochs MONOTONE increasing (round-9 bug: init
// epoch 301 made all later barriers no-ops -> races -> garbage).
// ---------------------------------------------------------------------------
__device__ __forceinline__ void gbar16(unsigned int* gfl, int s, unsigned int e) {
    __syncthreads();
    if (threadIdx.x < 64) {
        if (threadIdx.x == 0) ASTORE(&gfl[s * 16], e);
        const int peer = threadIdx.x & 15;
        while (ALOAD(&gfl[peer * 16]) < e)
            __builtin_amdgcn_s_sleep(1);
    }
    __syncthreads();
}
__device__ __forceinline__ void gbar8(unsigned int* gfl, int s, unsigned int e) {
    __syncthreads();
    if (threadIdx.x < 64) {
        if (threadIdx.x == 0) ASTORE(&gfl[s * 16], e);
        const int peer = threadIdx.x & 7;
        while (ALOAD(&gfl[peer * 16]) < e)
            __builtin_amdgcn_s_sleep(1);
    }
    __syncthreads();
}

// ---------------------------------------------------------------------------
// PRIMARY: 512 blocks x 512 threads (2 blocks/CU -> cross-group latency
// overlap). Block = (s = bid&15 slice, grp = bid>>4 -> 16 rows). LDS unioned
// across phases: 22 KB/block so 2 fit under any occupancy model.
// ---------------------------------------------------------------------------
__global__ void __launch_bounds__(512) k_persist16(
    const ushort_t* __restrict__ Wg, const float* __restrict__ bg,
    const ushort_t* __restrict__ Wzc, const float* __restrict__ bfold,
    const ushort_t* __restrict__ Wout, const float* __restrict__ b2,
    const float* __restrict__ bv, const ushort_t* __restrict__ Dfold,
    ushort_t* __restrict__ xh,          // [512][768]: inp | h(even) | h(odd)
    float* __restrict__ partA, float* __restrict__ partB,
    float* __restrict__ out, unsigned int* __restrict__ bars)
{
    __shared__ __align__(16) char smem[22144];
    ushort_t* sxh = (ushort_t*)smem;               // B: 16x520 u16 = 16640 B
    float*    sg  = (float*)(smem + 16640);        // B: 16x68 f32  -> 20992 B
    ushort_t* sa  = (ushort_t*)smem;               // C: 16x328 u16 = 10496 B
    ushort_t* zt  = (ushort_t*)(smem + 10496);     // C: 16x192 u16 -> 16640 B
    f4*       ra  = (f4*)smem;                     // A: 160 f4 = 2560 B
    float*    cl  = (float*)(smem + 20992);        // persistent 16x17 f32

    const int tid = threadIdx.x;
    const int w = tid >> 6, l = tid & 63, quad = l >> 4, lr = l & 15;
    const int s = blockIdx.x & 15, grp = blockIdx.x >> 4, m0 = grp * 16;
    unsigned int* xh_u  = (unsigned int*)xh;       // row stride 384 uints
    unsigned int* sxh_u = (unsigned int*)sxh;
    unsigned int* sa_u  = (unsigned int*)sa;
    unsigned int* zt_u  = (unsigned int*)zt;
    unsigned int* gfl = bars + grp * 256;          // 16 flags x 64 B
    unsigned int ep = 0;

    for (int i = tid; i < 16 * 17; i += 512) cl[i] = 0.f;
    if (tid < 384) {                               // zero own 24-uint xh slice
        int row = tid / 24, v = tid % 24;
        ASTORE(&xh_u[(size_t)(m0 + row) * 384 + s * 24 + v], 0u);
    }
    gbar16(gfl, s, ++ep);

    for (int t = 0; t <= TT; ++t) {
        const int hcur  = 256 + (t & 1) * 256;
        const int hprev = 256 + ((t + 1) & 1) * 256;
        float*       pw = (t & 1) ? partB : partA;
        const float* pr = (t & 1) ? partA : partB;

        // ============ Phase A: reduce 16-slice partials -> inp, out[t-1] ====
        if (t > 0) {
            int c0 = -1, row = 0, half = 0;
            if (tid < 320) {
                int task = tid >> 1;               // 160 tasks: 16 rows x 10.. no: 80x2
                half = tid & 1;
                row = task / 5;
                c0 = s * 20 + (task % 5) * 4;
                if (row >= 16) c0 = -1;
            }
            if (c0 >= 0 && c0 <= 264) {
                f4 a[4], b[4];
                const float* base = &pr[((size_t)(half * 8 * 512 + m0 + row)) * 320 + c0];
                aload16x4(a, base + (size_t)0 * 512 * 320, base + (size_t)1 * 512 * 320,
                             base + (size_t)2 * 512 * 320, base + (size_t)3 * 512 * 320);
                aload16x4(b, base + (size_t)4 * 512 * 320, base + (size_t)5 * 512 * 320,
                             base + (size_t)6 * 512 * 320, base + (size_t)7 * 512 * 320);
                ra[tid] = a[0] + a[1] + a[2] + a[3] + b[0] + b[1] + b[2] + b[3];
            }
            __syncthreads();
            if (tid < 80) {
                int r2 = tid / 5, cc0 = s * 20 + (tid % 5) * 4;
                if (cc0 <= 264) {
                    f4 tot = ra[tid * 2] + ra[tid * 2 + 1];
                    if (cc0 < 256) {
                        f4 bb = *(const f4*)&b2[cc0];
                        unsigned int v0 = (unsigned int)f2bf(fmaxf(tot[0] + bb[0], 0.f))
                            | ((unsigned int)f2bf(fmaxf(tot[1] + bb[1], 0.f)) << 16);
                        unsigned int v1 = (unsigned int)f2bf(fmaxf(tot[2] + bb[2], 0.f))
                            | ((unsigned int)f2bf(fmaxf(tot[3] + bb[3], 0.f)) << 16);
                        ASTORE(&xh_u[(size_t)(m0 + r2) * 384 + (cc0 >> 1)], v0);
                        ASTORE(&xh_u[(size_t)(m0 + r2) * 384 + (cc0 >> 1) + 1], v1);
                    } else {
                        #pragma unroll
                        for (int e = 0; e < 4; ++e) {
                            int col = cc0 + e;
                            if (col < NOUT)
                                out[(size_t)(m0 + r2) * (TT * NDD) + (t - 1) * NDD
                                    + (col - 256)] = sigf(tot[e] + bv[col - 256]);
                        }
                    }
                }
            }
            gbar16(gfl, s, ++ep);
        }
        if (t == TT) break;

        // ============ Phase B: gates slice (64 cols) + cell (16 h-cols) ====
        {
            int row0 = tid >> 6, q0 = tid & 63;
            const unsigned int* src0 = (q0 < 32)
                ? &xh_u[(size_t)(m0 + row0) * 384 + q0 * 4]
                : &xh_u[(size_t)(m0 + row0) * 384 + (hprev >> 1) + (q0 - 32) * 4];
            const unsigned int* src1 = (q0 < 32)
                ? &xh_u[(size_t)(m0 + row0 + 8) * 384 + q0 * 4]
                : &xh_u[(size_t)(m0 + row0 + 8) * 384 + (hprev >> 1) + (q0 - 32) * 4];
            u4 tmp[2];
            aload16x2(tmp, src0, src1);
            *(u4*)&sxh_u[row0 * 260 + q0 * 4] = tmp[0];
            *(u4*)&sxh_u[(row0 + 8) * 260 + q0 * 4] = tmp[1];
        }
        __syncthreads();
        {
            const int tile = w & 3, kh = w >> 2;    // 4 n-tiles x 2 k-halves
            f4 acc = {};
            const ushort_t* bp = Wg + (size_t)(s * 64 + tile * 16 + lr) * 512
                               + kh * 256 + quad * 8;
            const ushort_t* ap = &sxh[lr * 520 + kh * 256 + quad * 8];
            #pragma unroll
            for (int ks = 0; ks < 8; ++ks)
                acc = MFMA(*(const sh8*)(ap + ks * 32), *(const sh8*)(bp + ks * 32), acc);
            if (kh == 0) {
                #pragma unroll
                for (int r = 0; r < 4; ++r)
                    sg[(quad * 4 + r) * 68 + tile * 16 + lr] = acc[r];
            }
            __syncthreads();
            if (kh == 1) {
                #pragma unroll
                for (int r = 0; r < 4; ++r)
                    sg[(quad * 4 + r) * 68 + tile * 16 + lr] += acc[r];
            }
            __syncthreads();
            if (tid < 128) {
                int row = tid >> 3, jp2 = tid & 7;   // 2 h-cols per thread
                float g8[8];
                #pragma unroll
                for (int i = 0; i < 8; ++i)
                    g8[i] = sg[row * 68 + jp2 * 8 + i] + bg[s * 64 + jp2 * 8 + i];
                unsigned int pair = 0;
                #pragma unroll
                for (int h2 = 0; h2 < 2; ++h2) {
                    float ai = g8[h2 * 4 + 0], af = g8[h2 * 4 + 1];
                    float ag = g8[h2 * 4 + 2], ao = g8[h2 * 4 + 3];
                    int jc = jp2 * 2 + h2;           // local h col 0..15
                    float cc = sigf(af) * cl[row * 17 + jc] + sigf(ai) * tanhf(ag);
                    cl[row * 17 + jc] = cc;
                    float hh = sigf(ao) * tanhf(cc);
                    pair |= ((unsigned int)f2bf(hh)) << (16 * h2);
                }
                ASTORE(&xh_u[(size_t)(m0 + row) * 384 + (hcur >> 1) + s * 8 + jp2], pair);
            }
        }
        gbar16(gfl, s, ++ep);

        // ============ Phase C: z slice (176 cols) + out partials ===========
        if (tid < 128) {
            int row = tid >> 3, v = tid & 7;
            *(u4*)&sa_u[row * 164 + v * 4] =
                *(const u4*)&Dfold[((size_t)t * BSZ + m0 + row) * 64 + v * 8];
            zt_u[row * 96 + 88 + v] = 0u;            // zt pad cols 176..191
        }
        {
            int row = tid >> 5, v = tid & 31;        // 512 tasks = 16 x 32
            *(u4*)&sa_u[row * 164 + 32 + v * 4] =
                aload16(&xh_u[(size_t)(m0 + row) * 384 + (hcur >> 1) + v * 4]);
        }
        __syncthreads();
        for (int tl = w; tl < 11; tl += 8) {
            int n0g = s * 176 + tl * 16;
            f4 acc = {};
            const ushort_t* bp = Wzc + (size_t)(n0g + lr) * KZ + quad * 8;
            const ushort_t* ap = &sa[lr * 328 + quad * 8];
            #pragma unroll
            for (int ks = 0; ks < 10; ++ks)
                acc = MFMA(*(const sh8*)(ap + ks * 32), *(const sh8*)(bp + ks * 32), acc);
            float bia = bfold[n0g + lr];
            #pragma unroll
            for (int r = 0; r < 4; ++r)
                zt[(quad * 4 + r) * 192 + tl * 16 + lr] = f2bf(fmaxf(acc[r] + bia, 0.f));
        }
        __syncthreads();
        for (int tl = w; tl < 20; tl += 8) {
            int n0 = tl * 16;
            f4 acc = {};
            const ushort_t* bp = Wout + (size_t)(n0 + lr) * CAT + s * 176 + quad * 8;
            const ushort_t* ap = &zt[lr * 192 + quad * 8];
            #pragma unroll
            for (int ks = 0; ks < 6; ++ks)   // K 176..191 of zt is zero
                acc = MFMA(*(const sh8*)(ap + ks * 32), *(const sh8*)(bp + ks * 32), acc);
            #pragma unroll
            for (int r = 0; r < 4; ++r)
                ASTORE(&pw[((size_t)(s * 512 + m0 + quad * 4 + r)) * 320 + n0 + lr],
                       acc[r]);
        }
        gbar16(gfl, s, ++ep);
    }
}

// ---------------------------------------------------------------------------
// FALLBACK: round-10 kernel verbatim (proven 2346 us) — launched only if the
// 512-block cooperative launch is rejected.
// ---------------------------------------------------------------------------
__global__ void __launch_bounds__(1024) k_persist8(
    const ushort_t* __restrict__ Wg, const float* __restrict__ bg,
    const ushort_t* __restrict__ Wzc, const float* __restrict__ bfold,
    const ushort_t* __restrict__ Wout, const float* __restrict__ b2,
    const float* __restrict__ bv, const ushort_t* __restrict__ Dfold,
    ushort_t* __restrict__ xh,
    float* __restrict__ partA, float* __restrict__ partB,
    float* __restrict__ out, unsigned int* __restrict__ bars)
{
    __shared__ ushort_t sxh[16 * 520];
    __shared__ ushort_t sa[16 * 328];
    __shared__ ushort_t zt[16 * 360];
    __shared__ float    sg[16 * 132];
    __shared__ float    cl[16 * 33];

    const int bid = blockIdx.x;
    const int tid = threadIdx.x;
    const int w = tid >> 6, l = tid & 63, quad = l >> 4, lr = l & 15;
    const int s = bid & 7, grp = bid >> 3, m0 = grp * 16;
    unsigned int* xh_u  = (unsigned int*)xh;
    unsigned int* sxh_u = (unsigned int*)sxh;
    unsigned int* sa_u  = (unsigned int*)sa;
    unsigned int* gfl = bars + grp * 128;

    for (int i = tid; i < 16 * 33; i += 1024) cl[i] = 0.f;
    if (tid < 192) {
        int row = tid / 12, v = tid % 12;
        int q = s * 48 + v * 4;
        #pragma unroll
        for (int k = 0; k < 4; ++k)
            ASTORE(&xh_u[(size_t)(m0 + row) * 384 + q + k], 0u);
    }
    gbar8(gfl, s, 1);

    for (int t = 0; t < TT; ++t) {
        const int hcur  = 256 + (t & 1) * 256;
        const int hprev = 256 + ((t + 1) & 1) * 256;
        float*       pw = (t & 1) ? partB : partA;
        const float* pr = (t & 1) ? partA : partB;

        if (t > 0) {
            int row = -1, chunk = 0;
            if (s < 6 && tid < 160)      { row = tid / 10; chunk = tid % 10; }
            else if (s == 6 && tid < 64) { row = tid >> 2; chunk = tid & 3; }
            if (row >= 0) {
                const int c0 = s * 40 + chunk * 4;
                f4 a[4], b[4];
                const float* base = &pr[((size_t)(m0 + row)) * 320 + c0];
                aload16x4(a, base + (size_t)0 * 512 * 320, base + (size_t)1 * 512 * 320,
                             base + (size_t)2 * 512 * 320, base + (size_t)3 * 512 * 320);
                aload16x4(b, base + (size_t)4 * 512 * 320, base + (size_t)5 * 512 * 320,
                             base + (size_t)6 * 512 * 320, base + (size_t)7 * 512 * 320);
                f4 sum = a[0] + a[1] + a[2] + a[3] + b[0] + b[1] + b[2] + b[3];
                f4 bb = *(const f4*)&b2[c0];
                unsigned int v0 = (unsigned int)f2bf(fmaxf(sum[0] + bb[0], 0.f))
                    | ((unsigned int)f2bf(fmaxf(sum[1] + bb[1], 0.f)) << 16);
                unsigned int v1 = (unsigned int)f2bf(fmaxf(sum[2] + bb[2], 0.f))
                    | ((unsigned int)f2bf(fmaxf(sum[3] + bb[3], 0.f)) << 16);
                ASTORE(&xh_u[(size_t)(m0 + row) * 384 + (c0 >> 1)], v0);
                ASTORE(&xh_u[(size_t)(m0 + row) * 384 + (c0 >> 1) + 1], v1);
            }
            if (s == 6 && tid >= 512 && tid < 672) {
                int k = tid - 512, r2 = k / 10, col = k - r2 * 10;
                float sum = 0.f;
                #pragma unroll
                for (int s2 = 0; s2 < 8; ++s2)
                    sum += ALOAD(&pr[((size_t)(s2 * 512 + m0 + r2)) * 320 + 256 + col]);
                out[(size_t)(m0 + r2) * (TT * NDD) + (t - 1) * NDD + col] =
                    sigf(sum + bv[col]);
            }
            gbar8(gfl, s, 3 * t + 2);
        }

        {
            int row = tid >> 6, q4 = tid & 63;
            const unsigned int* src = (q4 < 32)
                ? &xh_u[(size_t)(m0 + row) * 384 + q4 * 4]
                : &xh_u[(size_t)(m0 + row) * 384 + (hprev >> 1) + (q4 - 32) * 4];
            *(u4*)&sxh_u[row * 260 + q4 * 4] = aload16(src);
        }
        __syncthreads();
        {
            const int tile = w & 7, kh = w >> 3;
            f4 acc = {};
            const ushort_t* bp = Wg + (size_t)(s * 128 + tile * 16 + lr) * 512
                               + kh * 256 + quad * 8;
            const ushort_t* ap = &sxh[lr * 520 + kh * 256 + quad * 8];
            #pragma unroll
            for (int ks = 0; ks < 8; ++ks)
                acc = MFMA(*(const sh8*)(ap + ks * 32), *(const sh8*)(bp + ks * 32), acc);
            if (kh == 0) {
                #pragma unroll
                for (int r = 0; r < 4; ++r)
                    sg[(quad * 4 + r) * 132 + tile * 16 + lr] = acc[r];
            }
            __syncthreads();
            if (kh == 1) {
                #pragma unroll
                for (int r = 0; r < 4; ++r)
                    sg[(quad * 4 + r) * 132 + tile * 16 + lr] += acc[r];
            }
            __syncthreads();
            if (tid < 256) {
                int row = tid >> 4, jp = tid & 15;
                float g8[8];
                #pragma unroll
                for (int i = 0; i < 8; ++i)
                    g8[i] = sg[row * 132 + jp * 8 + i] + bg[s * 128 + jp * 8 + i];
                unsigned int pair = 0;
                #pragma unroll
                for (int h2 = 0; h2 < 2; ++h2) {
                    float ai = g8[h2 * 4 + 0], af = g8[h2 * 4 + 1];
                    float ag = g8[h2 * 4 + 2], ao = g8[h2 * 4 + 3];
                    int jc = jp * 2 + h2;
                    float cc = sigf(af) * cl[row * 33 + jc] + sigf(ai) * tanhf(ag);
                    cl[row * 33 + jc] = cc;
                    float hh = sigf(ao) * tanhf(cc);
                    pair |= ((unsigned int)f2bf(hh)) << (16 * h2);
                }
                ASTORE(&xh_u[(size_t)(m0 + row) * 384 + (hcur >> 1) + s * 16 + jp], pair);
            }
        }
        gbar8(gfl, s, 3 * t + 3);

        if (tid < 128) {
            int row = tid >> 3, v = tid & 7;
            *(u4*)&sa_u[row * 164 + v * 4] =
                *(const u4*)&Dfold[((size_t)t * BSZ + m0 + row) * 64 + v * 8];
        } else if (tid >= 256 && tid < 768) {
            int k = tid - 256;
            int row = k >> 5, v = k & 31;
            *(u4*)&sa_u[row * 164 + 32 + v * 4] =
                aload16(&xh_u[(size_t)(m0 + row) * 384 + (hcur >> 1) + v * 4]);
        }
        __syncthreads();
        for (int tl = w; tl < 22; tl += 16) {
            int n0g = s * 352 + tl * 16;
            f4 acc = {};
            const ushort_t* bp = Wzc + (size_t)(n0g + lr) * KZ + quad * 8;
            const ushort_t* ap = &sa[lr * 328 + quad * 8];
            #pragma unroll
            for (int ks = 0; ks < 10; ++ks)
                acc = MFMA(*(const sh8*)(ap + ks * 32), *(const sh8*)(bp + ks * 32), acc);
            float bia = bfold[n0g + lr];
            #pragma unroll
            for (int r = 0; r < 4; ++r)
                zt[(quad * 4 + r) * 360 + tl * 16 + lr] = f2bf(fmaxf(acc[r] + bia, 0.f));
        }
        __syncthreads();
        for (int tl = w; tl < 20; tl += 16) {
            int n0 = tl * 16;
            f4 acc = {};
            const ushort_t* bp = Wout + (size_t)(n0 + lr) * CAT + s * 352 + quad * 8;
            const ushort_t* ap = &zt[lr * 360 + quad * 8];
            #pragma unroll
            for (int ks = 0; ks < 11; ++ks)
                acc = MFMA(*(const sh8*)(ap + ks * 32), *(const sh8*)(bp + ks * 32), acc);
            #pragma unroll
            for (int r = 0; r < 4; ++r)
                ASTORE(&pw[((size_t)(s * 512 + m0 + quad * 4 + r)) * 320 + n0 + lr],
                       acc[r]);
        }
        gbar8(gfl, s, 3 * t + 4);
    }

    if (s == 6 && tid < 160) {
        int row = tid / 10, col = tid - row * 10;
        float sum = 0.f;
        #pragma unroll
        for (int s2 = 0; s2 < 8; ++s2)
            sum += ALOAD(&partB[((size_t)(s2 * 512 + m0 + row)) * 320 + 256 + col]);
        out[(size_t)(m0 + row) * (TT * NDD) + (TT - 1) * NDD + col] = sigf(sum + bv[col]);
    }
}

// ---------------------------------------------------------------------------
extern "C" void kernel_launch(void* const* d_in, const int* in_sizes, int n_in,
                              void* d_out, int out_size, void* d_ws, size_t ws_size,
                              hipStream_t stream)
{
    const float* desc = (const float*)d_in[0];
    const float* Wd   = (const float*)d_in[1];
    const float* bd   = (const float*)d_in[2];
    const float* W1   = (const float*)d_in[3];
    const float* b1   = (const float*)d_in[4];
    const float* W2   = (const float*)d_in[5];
    const float* b2   = (const float*)d_in[6];
    const float* Wv   = (const float*)d_in[7];
    const float* bv   = (const float*)d_in[8];
    const float* Wih  = (const float*)d_in[9];
    const float* Whh  = (const float*)d_in[10];
    const float* bih  = (const float*)d_in[11];
    const float* bhh  = (const float*)d_in[12];
    float* out = (float*)d_out;

    char* base = (char*)d_ws;
    size_t off = 0;
    auto alloc = [&](size_t bytes) -> char* {
        char* p = base + off;
        off = (off + bytes + 255) & ~(size_t)255;
        return p;
    };
    ushort_t*     Wzc   = (ushort_t*)alloc((size_t)CAT * KZ * 2);
    float*        bfold = (float*)alloc(CAT * 4);
    ushort_t*     Wg    = (ushort_t*)alloc(1024 * 512 * 2);
    float*        bg    = (float*)alloc(1024 * 4);
    ushort_t*     Wout  = (ushort_t*)alloc((size_t)NOUTP * CAT * 2 + 256); // +pad: s=15 OF reads 32B past row 319
    ushort_t*     Dfold = (ushort_t*)alloc((size_t)TT * BSZ * 64 * 2);
    ushort_t*     xh    = (ushort_t*)alloc((size_t)BSZ * 768 * 2);
    float*        partA = (float*)alloc((size_t)16 * BSZ * NOUTP * 4);
    float*        partB = (float*)alloc((size_t)16 * BSZ * NOUTP * 4);
    unsigned int* bars16 = (unsigned int*)alloc(32 * 256 * 4);
    unsigned int* bars8  = (unsigned int*)alloc(32 * 128 * 4);

    hipMemsetAsync(bars16, 0, 32 * 256 * 4, stream);
    hipMemsetAsync(bars8,  0, 32 * 128 * 4, stream);

    k_fold  <<<CAT, 64, 0, stream>>>(W1, Wd, bd, b1, Wzc, bfold);
    k_dfold <<<(TT * BSZ * 64) / 256, 256, 0, stream>>>(desc, Dfold);
    k_prep_g<<<(1024 * 512) / 256, 256, 0, stream>>>(Wih, Whh, bih, bhh, Wg, bg);
    k_prep_o<<<(NOUTP * CAT) / 256, 256, 0, stream>>>(W2, Wv, Wout);

    void* args16[] = {
        (void*)&Wg, (void*)&bg, (void*)&Wzc, (void*)&bfold, (void*)&Wout,
        (void*)&b2, (void*)&bv, (void*)&Dfold, (void*)&xh,
        (void*)&partA, (void*)&partB, (void*)&out, (void*)&bars16
    };
    hipError_t err = hipLaunchCooperativeKernel((const void*)k_persist16,
                                                dim3(512), dim3(512),
                                                args16, 0, stream);
    if (err != hipSuccess) {
        void* args8[] = {
            (void*)&Wg, (void*)&bg, (void*)&Wzc, (void*)&bfold, (void*)&Wout,
            (void*)&b2, (void*)&bv, (void*)&Dfold, (void*)&xh,
            (void*)&partA, (void*)&partB, (void*)&out, (void*)&bars8
        };
        hipLaunchCooperativeKernel((const void*)k_persist8, dim3(256), dim3(1024),
                                   args8, 0, stream);
    }
}